// Round 4
// baseline (2288.740 us; speedup 1.0000x reference)
//
#include <hip/hip_runtime.h>
#include <stdint.h>

#define USER_NUM 100000
#define ITEM_NUM 200000
#define N_NODES  300000
#define EMB      64
#define NNZ      2000000
#define BATCH    4096
#define R1M      1000000u        // NNZ/2, threefry pair offset for edge dropout
#define HALF_MSG 9600000u        // N_NODES*EMB/2, pair offset for msg dropout
#define INVK     1.1111111111111112f  // 1/0.9

// ---------------- threefry2x32 (exact JAX replica) ----------------
__host__ __device__ inline uint32_t rotl32(uint32_t v, int r) {
    return (v << r) | (v >> (32 - r));
}

__host__ __device__ inline void threefry2x32(uint32_t k0, uint32_t k1,
                                             uint32_t x0, uint32_t x1,
                                             uint32_t& o0, uint32_t& o1) {
    uint32_t k2 = k0 ^ k1 ^ 0x1BD11BDAu;
    x0 += k0; x1 += k1;
#define TF_R(r) { x0 += x1; x1 = rotl32(x1, r); x1 ^= x0; }
    TF_R(13) TF_R(15) TF_R(26) TF_R(6)
    x0 += k1; x1 += k2 + 1u;
    TF_R(17) TF_R(29) TF_R(16) TF_R(24)
    x0 += k2; x1 += k0 + 2u;
    TF_R(13) TF_R(15) TF_R(26) TF_R(6)
    x0 += k0; x1 += k1 + 3u;
    TF_R(17) TF_R(29) TF_R(16) TF_R(24)
    x0 += k1; x1 += k2 + 4u;
    TF_R(13) TF_R(15) TF_R(26) TF_R(6)
    x0 += k2; x1 += k0 + 5u;
#undef TF_R
    o0 = x0; o1 = x1;
}

__host__ __device__ inline float tf_uniform(uint32_t bits) {
    uint32_t fb = (bits >> 9) | 0x3f800000u;
    return __builtin_bit_cast(float, fb) - 1.0f;
}

// edge-dropout keep test for original edge index e (bit-exact JAX bernoulli)
__device__ inline bool edge_keep(uint32_t e, uint32_t kn0, uint32_t kn1) {
    uint32_t x0 = (e < R1M) ? e : e - R1M;
    uint32_t o0, o1;
    threefry2x32(kn0, kn1, x0, x0 + R1M, o0, o1);
    uint32_t bits = (e < R1M) ? o0 : o1;
    return tf_uniform(bits) < 0.9f;
}

// ---------------- bf16 helpers ----------------
__device__ inline float bf2f(uint16_t u) {
    uint32_t x = ((uint32_t)u) << 16;
    return __builtin_bit_cast(float, x);
}
__device__ inline uint16_t f2bf(float f) {   // round-to-nearest-even
    uint32_t x = __builtin_bit_cast(uint32_t, f);
    uint32_t r = (x + 0x7FFFu + ((x >> 16) & 1u)) >> 16;
    return (uint16_t)r;
}

// ---------------- CSR build (kept edges only: dropout folded in) -----------
__global__ __launch_bounds__(256) void k_hist(const int* __restrict__ erow,
                                              uint32_t* __restrict__ cnt,
                                              uint32_t kn0, uint32_t kn1) {
    int e = blockIdx.x * 256 + threadIdx.x;
    if (e < NNZ && edge_keep((uint32_t)e, kn0, kn1))
        atomicAdd(&cnt[erow[e]], 1u);
}

__global__ __launch_bounds__(1024) void k_scan1(uint32_t* __restrict__ cnt,
                                                uint32_t* __restrict__ partials) {
    __shared__ uint32_t sh[1024];
    int t = threadIdx.x;
    int i = blockIdx.x * 1024 + t;
    uint32_t x = (i < N_NODES) ? cnt[i] : 0u;
    sh[t] = x;
    __syncthreads();
    for (int off = 1; off < 1024; off <<= 1) {
        uint32_t y = (t >= off) ? sh[t - off] : 0u;
        __syncthreads();
        sh[t] += y;
        __syncthreads();
    }
    if (i < N_NODES) cnt[i] = sh[t] - x;
    if (t == 1023) partials[blockIdx.x] = sh[t];
}

__global__ __launch_bounds__(1024) void k_scan2(uint32_t* __restrict__ partials,
                                                int nblocks) {
    __shared__ uint32_t sh[1024];
    int t = threadIdx.x;
    uint32_t x = (t < nblocks) ? partials[t] : 0u;
    sh[t] = x;
    __syncthreads();
    for (int off = 1; off < 1024; off <<= 1) {
        uint32_t y = (t >= off) ? sh[t - off] : 0u;
        __syncthreads();
        sh[t] += y;
        __syncthreads();
    }
    if (t < nblocks) partials[t] = sh[t] - x;
}

__global__ __launch_bounds__(1024) void k_scan3(uint32_t* __restrict__ cnt,
                                                const uint32_t* __restrict__ partials) {
    int i = blockIdx.x * 1024 + threadIdx.x;
    if (i < N_NODES) cnt[i] += partials[blockIdx.x];
}

__global__ __launch_bounds__(256) void k_place(const int* __restrict__ erow,
                                               uint32_t* __restrict__ cursor,
                                               uint32_t* __restrict__ eidx,
                                               uint32_t kn0, uint32_t kn1) {
    int e = blockIdx.x * 256 + threadIdx.x;
    if (e >= NNZ) return;
    if (!edge_keep((uint32_t)e, kn0, kn1)) return;
    int r = erow[e];
    uint32_t pos = atomicAdd(&cursor[r], 1u);
    eidx[pos] = (uint32_t)e;
}

// ---------------- fused layer ----------------------------------------------
// Wave handles 8 rows: gather (bf16 or fp32 src) -> LDS-weight dense ->
// leaky -> msg-dropout -> bf16 store. Weights broadcast from LDS (no spill).
__global__ __launch_bounds__(256) void k_layer(
        const uint16_t* __restrict__ srcB,       // bf16 src (layers 2,3)
        const float* __restrict__ uembF,         // fp32 src (layer 1)
        const float* __restrict__ iembF,
        uint16_t* __restrict__ dst,
        const uint32_t* __restrict__ cursor, const uint32_t* __restrict__ eidx,
        const int* __restrict__ ecol, const float* __restrict__ evals,
        const float* __restrict__ Wg, const float* __restrict__ bg,
        const float* __restrict__ Wb, const float* __restrict__ bb,
        uint32_t km0, uint32_t km1, int srcF32) {
    __shared__ float wgs[64][64];
    __shared__ float wbs[64][64];
    int tid = threadIdx.x;
    for (int i = tid; i < 4096; i += 256) {
        wgs[i >> 6][i & 63] = Wg[i];
        wbs[i >> 6][i & 63] = Wb[i];
    }
    __syncthreads();
    int lane = tid & 63;
    int wave = (blockIdx.x * 256 + tid) >> 6;
    int nw = (gridDim.x * 256) >> 6;
    float bgl = bg[lane], bbl = bb[lane];

    for (int n0 = wave * 8; n0 < N_NODES; n0 += nw * 8) {
        float acc[8], tt[8];
        // ---- gather phase ----
#pragma unroll
        for (int r = 0; r < 8; ++r) {
            int n = n0 + r;
            uint32_t end = cursor[n];
            uint32_t start = (n > 0) ? cursor[n - 1] : 0u;
            float a = 0.0f;
            for (uint32_t base = start; base < end; base += 64) {
                int m = (int)min(64u, end - base);
                int c = 0; float v = 0.0f;
                if (lane < m) {
                    uint32_t ei = eidx[base + lane];
                    c = ecol[ei];
                    v = evals[ei] * INVK;   // all stored edges are kept
                }
                for (int j0 = 0; j0 < m; j0 += 8) {
#pragma unroll
                    for (int u = 0; u < 8; ++u) {
                        if (j0 + u < m) {
                            float vj = __shfl(v, j0 + u, 64);
                            int   cj = __shfl(c, j0 + u, 64);
                            float g;
                            if (srcF32)
                                g = (cj < USER_NUM)
                                        ? uembF[(size_t)cj * 64 + lane]
                                        : iembF[(size_t)(cj - USER_NUM) * 64 + lane];
                            else
                                g = bf2f(srcB[(size_t)cj * 64 + lane]);
                            a = fmaf(vj, g, a);
                        }
                    }
                }
            }
            acc[r] = a;
        }
        // ---- ego (bi term) ----
#pragma unroll
        for (int r = 0; r < 8; ++r) {
            int n = n0 + r;
            float e;
            if (srcF32)
                e = (n < USER_NUM) ? uembF[(size_t)n * 64 + lane]
                                   : iembF[(size_t)(n - USER_NUM) * 64 + lane];
            else
                e = bf2f(srcB[(size_t)n * 64 + lane]);
            tt[r] = e * acc[r];
        }
        // ---- dense: LDS weight broadcast, readlane row broadcast ----
        float a1[8], a2[8];
#pragma unroll
        for (int r = 0; r < 8; ++r) { a1[r] = bgl; a2[r] = bbl; }
#pragma unroll
        for (int k = 0; k < 64; ++k) {
            float wgk = wgs[k][lane];
            float wbk = wbs[k][lane];
#pragma unroll
            for (int r = 0; r < 8; ++r) {
                float sk = __builtin_bit_cast(float,
                    __builtin_amdgcn_readlane(__builtin_bit_cast(int, acc[r]), k));
                float tk = __builtin_bit_cast(float,
                    __builtin_amdgcn_readlane(__builtin_bit_cast(int, tt[r]), k));
                a1[r] = fmaf(sk, wgk, a1[r]);
                a2[r] = fmaf(tk, wbk, a2[r]);
            }
        }
        // ---- activation + message dropout + store ----
#pragma unroll
        for (int r = 0; r < 8; ++r) {
            int n = n0 + r;
            float h = a1[r] + a2[r];
            h = (h >= 0.0f) ? h : 0.2f * h;
            uint32_t j = (uint32_t)n * 64u + (uint32_t)lane;
            uint32_t x0 = (j < HALF_MSG) ? j : j - HALF_MSG;
            uint32_t o0, o1;
            threefry2x32(km0, km1, x0, x0 + HALF_MSG, o0, o1);
            uint32_t bits = (j < HALF_MSG) ? o0 : o1;
            bool keep = tf_uniform(bits) < 0.9f;
            dst[(size_t)n * 64 + lane] = f2bf(keep ? h * INVK : 0.0f);
        }
    }
}

// ---------------- batch accumulation & finalize ----------------
__device__ inline float wred64(float v) {
#pragma unroll
    for (int m = 32; m >= 1; m >>= 1) v += __shfl_xor(v, m, 64);
    return v;
}

__global__ __launch_bounds__(256) void k_segacc(const void* __restrict__ ua_,
                                                const void* __restrict__ ia_,
                                                const int* __restrict__ uid,
                                                const int* __restrict__ iid,
                                                const int* __restrict__ nid,
                                                float* __restrict__ dotp,
                                                float* __restrict__ dotn,
                                                float* __restrict__ sqs,
                                                int normalize, int f32) {
    int gt = blockIdx.x * 256 + threadIdx.x;
    int w = gt >> 6, lane = gt & 63;
    if (w >= BATCH) return;
    int u = uid[w], p = iid[w], n = nid[w];
    float eu, ep, en;
    if (f32) {
        const float* ua = (const float*)ua_;
        const float* ia = (const float*)ia_;
        eu = ua[(size_t)u * EMB + lane];
        ep = ia[(size_t)p * EMB + lane];
        en = ia[(size_t)n * EMB + lane];
    } else {
        const uint16_t* ua = (const uint16_t*)ua_;
        const uint16_t* ia = (const uint16_t*)ia_;
        eu = bf2f(ua[(size_t)u * EMB + lane]);
        ep = bf2f(ia[(size_t)p * EMB + lane]);
        en = bf2f(ia[(size_t)n * EMB + lane]);
    }
    if (normalize) {
        float su = wred64(eu * eu);
        float sp = wred64(ep * ep);
        float sn = wred64(en * en);
        eu /= fmaxf(sqrtf(su), 1e-12f);
        ep /= fmaxf(sqrtf(sp), 1e-12f);
        en /= fmaxf(sqrtf(sn), 1e-12f);
    }
    float dp = wred64(eu * ep);
    float dn = wred64(eu * en);
    float s3 = wred64(eu * eu + ep * ep + en * en);
    if (lane == 0) {
        dotp[w] += dp;
        dotn[w] += dn;
        sqs[w]  += s3;
    }
}

__global__ __launch_bounds__(256) void k_finalize(const float* __restrict__ dotp,
                                                  const float* __restrict__ dotn,
                                                  const float* __restrict__ sqs,
                                                  float* __restrict__ out) {
    __shared__ float smf[256], ssq[256];
    int t = threadIdx.x;
    float mf = 0.0f, s = 0.0f;
    for (int b = t; b < BATCH; b += 256) {
        float x = dotp[b] - dotn[b];
        float ls = fminf(x, 0.0f) - log1pf(expf(-fabsf(x)));
        mf += ls;
        s += sqs[b];
    }
    smf[t] = mf; ssq[t] = s;
    __syncthreads();
    for (int off = 128; off > 0; off >>= 1) {
        if (t < off) { smf[t] += smf[t + off]; ssq[t] += ssq[t + off]; }
        __syncthreads();
    }
    if (t == 0) {
        float mf_loss = -smf[0] / (float)BATCH;
        float reg = 0.5f * ssq[0];
        float emb_loss = (float)1e-4 * reg / (float)BATCH;
        out[0] = mf_loss + emb_loss;
        out[1] = mf_loss;
        out[2] = emb_loss;
    }
}

// ---------------- launch ----------------
extern "C" void kernel_launch(void* const* d_in, const int* in_sizes, int n_in,
                              void* d_out, int out_size, void* d_ws, size_t ws_size,
                              hipStream_t stream) {
    const int*   erow  = (const int*)d_in[0];
    const int*   ecol  = (const int*)d_in[1];
    const float* evals = (const float*)d_in[2];
    const float* uemb  = (const float*)d_in[3];
    const float* iemb  = (const float*)d_in[4];
    const int*   uid   = (const int*)d_in[5];
    const int*   iid   = (const int*)d_in[6];
    const int*   nid   = (const int*)d_in[7];
    const float* Wg[3] = {(const float*)d_in[8],  (const float*)d_in[12], (const float*)d_in[16]};
    const float* bg[3] = {(const float*)d_in[9],  (const float*)d_in[13], (const float*)d_in[17]};
    const float* Wb[3] = {(const float*)d_in[10], (const float*)d_in[14], (const float*)d_in[18]};
    const float* bb[3] = {(const float*)d_in[11], (const float*)d_in[15], (const float*)d_in[19]};

    // workspace layout (~86.1 MB)
    uint16_t* bufA     = (uint16_t*)d_ws;                       // 19.2M bf16
    uint16_t* bufB     = bufA + (size_t)N_NODES * EMB;          // 19.2M bf16
    uint32_t* cursor   = (uint32_t*)(bufB + (size_t)N_NODES * EMB); // 300000 u32
    uint32_t* eidx     = cursor + N_NODES;                      // 2M u32
    uint32_t* partials = eidx + NNZ;                            // 1024
    float*    dotp     = (float*)(partials + 1024);             // 4096
    float*    dotn     = dotp + BATCH;
    float*    sqs      = dotn + BATCH;
    size_t needed = (size_t)N_NODES * EMB * 2 * 2
                  + ((size_t)N_NODES + NNZ + 1024 + 3 * BATCH) * 4;
    if (ws_size < needed) return;

    // host-side JAX key derivation: key(42) = (0,42)
    uint32_t a0, b0, a1, b1;
    threefry2x32(0u, 42u, 0u, 2u, a0, b0);   // split block 0
    threefry2x32(0u, 42u, 1u, 3u, a1, b1);   // split block 1
    uint32_t knode0 = a0, knode1 = a1;       // k_node
    uint32_t kmsg0  = b0, kmsg1  = b1;       // k_msg
    uint32_t mk[6];
    for (uint32_t k = 0; k < 3; ++k)
        threefry2x32(kmsg0, kmsg1, 0u, k, mk[2 * k], mk[2 * k + 1]);

    hipMemsetAsync(cursor, 0, (size_t)N_NODES * 4, stream);
    hipMemsetAsync(dotp, 0, 3 * BATCH * 4, stream);

    // CSR build over KEPT edges only (edge dropout folded into hist/place)
    const int SCAN_BLOCKS = (N_NODES + 1023) / 1024;  // 293
    k_hist<<<(NNZ + 255) / 256, 256, 0, stream>>>(erow, cursor, knode0, knode1);
    k_scan1<<<SCAN_BLOCKS, 1024, 0, stream>>>(cursor, partials);
    k_scan2<<<1, 1024, 0, stream>>>(partials, SCAN_BLOCKS);
    k_scan3<<<SCAN_BLOCKS, 1024, 0, stream>>>(cursor, partials);
    k_place<<<(NNZ + 255) / 256, 256, 0, stream>>>(erow, cursor, eidx, knode0, knode1);

    // segment 0: raw initial embeddings (fp32, no normalization)
    k_segacc<<<BATCH * 64 / 256, 256, 0, stream>>>(uemb, iemb, uid, iid, nid,
                                                   dotp, dotn, sqs, 0, 1);

    // layer 1: fp32 (uemb,iemb) -> bufA ; layer 2: bufA -> bufB ; layer 3: bufB -> bufA
    k_layer<<<1280, 256, 0, stream>>>(nullptr, uemb, iemb, bufA, cursor, eidx,
                                      ecol, evals, Wg[0], bg[0], Wb[0], bb[0],
                                      mk[0], mk[1], 1);
    k_segacc<<<BATCH * 64 / 256, 256, 0, stream>>>(bufA, bufA + (size_t)USER_NUM * EMB,
                                                   uid, iid, nid, dotp, dotn, sqs, 1, 0);
    k_layer<<<1280, 256, 0, stream>>>(bufA, nullptr, nullptr, bufB, cursor, eidx,
                                      ecol, evals, Wg[1], bg[1], Wb[1], bb[1],
                                      mk[2], mk[3], 0);
    k_segacc<<<BATCH * 64 / 256, 256, 0, stream>>>(bufB, bufB + (size_t)USER_NUM * EMB,
                                                   uid, iid, nid, dotp, dotn, sqs, 1, 0);
    k_layer<<<1280, 256, 0, stream>>>(bufB, nullptr, nullptr, bufA, cursor, eidx,
                                      ecol, evals, Wg[2], bg[2], Wb[2], bb[2],
                                      mk[4], mk[5], 0);
    k_segacc<<<BATCH * 64 / 256, 256, 0, stream>>>(bufA, bufA + (size_t)USER_NUM * EMB,
                                                   uid, iid, nid, dotp, dotn, sqs, 1, 0);

    k_finalize<<<1, 256, 0, stream>>>(dotp, dotn, sqs, (float*)d_out);
}

// Round 5
// 1102.141 us; speedup vs baseline: 2.0766x; 2.0766x over previous
//
#include <hip/hip_runtime.h>
#include <stdint.h>

#define USER_NUM 100000
#define ITEM_NUM 200000
#define N_NODES  300000
#define EMB      64
#define NNZ      2000000
#define BATCH    4096
#define R1M      1000000u        // NNZ/2, threefry pair offset for edge dropout
#define HALF_MSG 9600000u        // N_NODES*EMB/2, pair offset for msg dropout
#define INVK     1.1111111111111112f  // 1/0.9

// ---------------- threefry2x32 (exact JAX replica) ----------------
__host__ __device__ inline uint32_t rotl32(uint32_t v, int r) {
    return (v << r) | (v >> (32 - r));
}

__host__ __device__ inline void threefry2x32(uint32_t k0, uint32_t k1,
                                             uint32_t x0, uint32_t x1,
                                             uint32_t& o0, uint32_t& o1) {
    uint32_t k2 = k0 ^ k1 ^ 0x1BD11BDAu;
    x0 += k0; x1 += k1;
#define TF_R(r) { x0 += x1; x1 = rotl32(x1, r); x1 ^= x0; }
    TF_R(13) TF_R(15) TF_R(26) TF_R(6)
    x0 += k1; x1 += k2 + 1u;
    TF_R(17) TF_R(29) TF_R(16) TF_R(24)
    x0 += k2; x1 += k0 + 2u;
    TF_R(13) TF_R(15) TF_R(26) TF_R(6)
    x0 += k0; x1 += k1 + 3u;
    TF_R(17) TF_R(29) TF_R(16) TF_R(24)
    x0 += k1; x1 += k2 + 4u;
    TF_R(13) TF_R(15) TF_R(26) TF_R(6)
    x0 += k2; x1 += k0 + 5u;
#undef TF_R
    o0 = x0; o1 = x1;
}

__host__ __device__ inline float tf_uniform(uint32_t bits) {
    uint32_t fb = (bits >> 9) | 0x3f800000u;
    return __builtin_bit_cast(float, fb) - 1.0f;
}

__device__ inline bool edge_keep(uint32_t e, uint32_t kn0, uint32_t kn1) {
    uint32_t x0 = (e < R1M) ? e : e - R1M;
    uint32_t o0, o1;
    threefry2x32(kn0, kn1, x0, x0 + R1M, o0, o1);
    uint32_t bits = (e < R1M) ? o0 : o1;
    return tf_uniform(bits) < 0.9f;
}

// ---------------- bf16 helpers ----------------
__device__ inline float bf2f(uint16_t u) {
    uint32_t x = ((uint32_t)u) << 16;
    return __builtin_bit_cast(float, x);
}
__device__ inline uint16_t f2bf(float f) {   // round-to-nearest-even
    uint32_t x = __builtin_bit_cast(uint32_t, f);
    uint32_t r = (x + 0x7FFFu + ((x >> 16) & 1u)) >> 16;
    return (uint16_t)r;
}

// ---------------- ego init: concat(uemb,iemb) -> bf16 ----------------
__global__ __launch_bounds__(256) void k_conv(const float* __restrict__ u,
                                              const float* __restrict__ it,
                                              uint16_t* __restrict__ dst) {
    int i = blockIdx.x * 256 + threadIdx.x;     // quad index
    const int TOT = N_NODES * EMB / 4;          // 4.8M
    if (i >= TOT) return;
    const int UQ = USER_NUM * EMB / 4;
    float4 f = (i < UQ) ? ((const float4*)u)[i] : ((const float4*)it)[i - UQ];
    ushort4 o;
    o.x = f2bf(f.x); o.y = f2bf(f.y); o.z = f2bf(f.z); o.w = f2bf(f.w);
    ((ushort4*)dst)[i] = o;
}

// ---------------- CSR build (kept edges only) ----------------
__global__ __launch_bounds__(256) void k_hist(const int* __restrict__ erow,
                                              uint32_t* __restrict__ cnt,
                                              uint32_t kn0, uint32_t kn1) {
    int e = blockIdx.x * 256 + threadIdx.x;
    if (e < NNZ && edge_keep((uint32_t)e, kn0, kn1))
        atomicAdd(&cnt[erow[e]], 1u);
}

__global__ __launch_bounds__(1024) void k_scan1(uint32_t* __restrict__ cnt,
                                                uint32_t* __restrict__ partials) {
    __shared__ uint32_t sh[1024];
    int t = threadIdx.x;
    int i = blockIdx.x * 1024 + t;
    uint32_t x = (i < N_NODES) ? cnt[i] : 0u;
    sh[t] = x;
    __syncthreads();
    for (int off = 1; off < 1024; off <<= 1) {
        uint32_t y = (t >= off) ? sh[t - off] : 0u;
        __syncthreads();
        sh[t] += y;
        __syncthreads();
    }
    if (i < N_NODES) cnt[i] = sh[t] - x;
    if (t == 1023) partials[blockIdx.x] = sh[t];
}

__global__ __launch_bounds__(1024) void k_scan2(uint32_t* __restrict__ partials,
                                                int nblocks) {
    __shared__ uint32_t sh[1024];
    int t = threadIdx.x;
    uint32_t x = (t < nblocks) ? partials[t] : 0u;
    sh[t] = x;
    __syncthreads();
    for (int off = 1; off < 1024; off <<= 1) {
        uint32_t y = (t >= off) ? sh[t - off] : 0u;
        __syncthreads();
        sh[t] += y;
        __syncthreads();
    }
    if (t < nblocks) partials[t] = sh[t] - x;
}

__global__ __launch_bounds__(1024) void k_scan3(uint32_t* __restrict__ cnt,
                                                const uint32_t* __restrict__ partials) {
    int i = blockIdx.x * 1024 + threadIdx.x;
    if (i < N_NODES) cnt[i] += partials[blockIdx.x];
}

// writes packed (col, val*INVK) at sorted position
__global__ __launch_bounds__(256) void k_place(const int* __restrict__ erow,
                                               const int* __restrict__ ecol,
                                               const float* __restrict__ evals,
                                               uint32_t* __restrict__ cursor,
                                               uint2* __restrict__ cv,
                                               uint32_t kn0, uint32_t kn1) {
    int e = blockIdx.x * 256 + threadIdx.x;
    if (e >= NNZ) return;
    if (!edge_keep((uint32_t)e, kn0, kn1)) return;
    int r = erow[e];
    uint32_t pos = atomicAdd(&cursor[r], 1u);
    uint2 p;
    p.x = (uint32_t)ecol[e];
    p.y = __builtin_bit_cast(uint32_t, evals[e] * INVK);
    cv[pos] = p;
}

// -------- SPMV: side[n] = sum_e v[e] * ego[col[e]]  (wave per row, bf16) ----
__global__ __launch_bounds__(256) void k_spmv(const uint16_t* __restrict__ ego,
                                              float* __restrict__ side,
                                              const uint32_t* __restrict__ cursor,
                                              const uint2* __restrict__ cv) {
    int lane = threadIdx.x & 63;
    int wave = (blockIdx.x * 256 + threadIdx.x) >> 6;
    int nw = (gridDim.x * 256) >> 6;
    for (int n = wave; n < N_NODES; n += nw) {
        uint32_t end = cursor[n];
        uint32_t start = (n > 0) ? cursor[n - 1] : 0u;
        float acc = 0.0f;
        for (uint32_t base = start; base < end; base += 64) {
            int m = (int)min(64u, end - base);
            int c = 0; float v = 0.0f;
            if (lane < m) {
                uint2 p = cv[base + lane];
                c = (int)p.x;
                v = __builtin_bit_cast(float, p.y);
            }
            for (int j0 = 0; j0 < m; j0 += 8) {
                int jm = min(8, m - j0);
                float g[8];
#pragma unroll
                for (int u = 0; u < 8; ++u)
                    if (u < jm) {
                        int cj = __shfl(c, j0 + u, 64);
                        g[u] = bf2f(ego[(size_t)cj * 64 + lane]);
                    }
#pragma unroll
                for (int u = 0; u < 8; ++u)
                    if (u < jm) {
                        float vj = __shfl(v, j0 + u, 64);
                        acc = fmaf(vj, g[u], acc);
                    }
            }
        }
        side[(size_t)n * 64 + lane] = acc;
    }
}

// -------- dense: LDS weights, 8 rows/wave, in-place bf16 ego ----------------
__global__ __launch_bounds__(256) void k_dense(uint16_t* __restrict__ ego,
                                               const float* __restrict__ side,
                                               const float* __restrict__ Wg,
                                               const float* __restrict__ bg,
                                               const float* __restrict__ Wb,
                                               const float* __restrict__ bb,
                                               uint32_t km0, uint32_t km1) {
    __shared__ float wgs[64][64];
    __shared__ float wbs[64][64];
    int tid = threadIdx.x;
    for (int i = tid; i < 4096; i += 256) {
        wgs[i >> 6][i & 63] = Wg[i];
        wbs[i >> 6][i & 63] = Wb[i];
    }
    __syncthreads();
    int lane = tid & 63;
    int wave = (blockIdx.x * 256 + tid) >> 6;
    int nw = (gridDim.x * 256) >> 6;
    float bgl = bg[lane], bbl = bb[lane];

    for (int n0 = wave * 8; n0 < N_NODES; n0 += nw * 8) {   // 300000 % 8 == 0
        float s[8], t[8];
#pragma unroll
        for (int r = 0; r < 8; ++r) {
            int n = n0 + r;
            s[r] = side[(size_t)n * 64 + lane];
            t[r] = bf2f(ego[(size_t)n * 64 + lane]) * s[r];
        }
        float a1[8], a2[8];
#pragma unroll
        for (int r = 0; r < 8; ++r) { a1[r] = bgl; a2[r] = bbl; }
#pragma unroll
        for (int k = 0; k < 64; ++k) {
            float wgk = wgs[k][lane];
            float wbk = wbs[k][lane];
#pragma unroll
            for (int r = 0; r < 8; ++r) {
                float sk = __builtin_bit_cast(float,
                    __builtin_amdgcn_readlane(__builtin_bit_cast(int, s[r]), k));
                float tk = __builtin_bit_cast(float,
                    __builtin_amdgcn_readlane(__builtin_bit_cast(int, t[r]), k));
                a1[r] = fmaf(sk, wgk, a1[r]);
                a2[r] = fmaf(tk, wbk, a2[r]);
            }
        }
#pragma unroll
        for (int r = 0; r < 8; ++r) {
            int n = n0 + r;
            float h = a1[r] + a2[r];
            h = (h >= 0.0f) ? h : 0.2f * h;
            uint32_t j = (uint32_t)n * 64u + (uint32_t)lane;
            uint32_t x0 = (j < HALF_MSG) ? j : j - HALF_MSG;
            uint32_t o0, o1;
            threefry2x32(km0, km1, x0, x0 + HALF_MSG, o0, o1);
            uint32_t bits = (j < HALF_MSG) ? o0 : o1;
            bool keep = tf_uniform(bits) < 0.9f;
            ego[(size_t)n * 64 + lane] = f2bf(keep ? h * INVK : 0.0f);
        }
    }
}

// ---------------- batch accumulation & finalize ----------------
__device__ inline float wred64(float v) {
#pragma unroll
    for (int m = 32; m >= 1; m >>= 1) v += __shfl_xor(v, m, 64);
    return v;
}

__global__ __launch_bounds__(256) void k_segacc(const void* __restrict__ ua_,
                                                const void* __restrict__ ia_,
                                                const int* __restrict__ uid,
                                                const int* __restrict__ iid,
                                                const int* __restrict__ nid,
                                                float* __restrict__ dotp,
                                                float* __restrict__ dotn,
                                                float* __restrict__ sqs,
                                                int normalize, int f32) {
    int gt = blockIdx.x * 256 + threadIdx.x;
    int w = gt >> 6, lane = gt & 63;
    if (w >= BATCH) return;
    int u = uid[w], p = iid[w], n = nid[w];
    float eu, ep, en;
    if (f32) {
        const float* ua = (const float*)ua_;
        const float* ia = (const float*)ia_;
        eu = ua[(size_t)u * EMB + lane];
        ep = ia[(size_t)p * EMB + lane];
        en = ia[(size_t)n * EMB + lane];
    } else {
        const uint16_t* ua = (const uint16_t*)ua_;
        const uint16_t* ia = (const uint16_t*)ia_;
        eu = bf2f(ua[(size_t)u * EMB + lane]);
        ep = bf2f(ia[(size_t)p * EMB + lane]);
        en = bf2f(ia[(size_t)n * EMB + lane]);
    }
    if (normalize) {
        float su = wred64(eu * eu);
        float sp = wred64(ep * ep);
        float sn = wred64(en * en);
        eu /= fmaxf(sqrtf(su), 1e-12f);
        ep /= fmaxf(sqrtf(sp), 1e-12f);
        en /= fmaxf(sqrtf(sn), 1e-12f);
    }
    float dp = wred64(eu * ep);
    float dn = wred64(eu * en);
    float s3 = wred64(eu * eu + ep * ep + en * en);
    if (lane == 0) {
        dotp[w] += dp;
        dotn[w] += dn;
        sqs[w]  += s3;
    }
}

__global__ __launch_bounds__(256) void k_finalize(const float* __restrict__ dotp,
                                                  const float* __restrict__ dotn,
                                                  const float* __restrict__ sqs,
                                                  float* __restrict__ out) {
    __shared__ float smf[256], ssq[256];
    int t = threadIdx.x;
    float mf = 0.0f, s = 0.0f;
    for (int b = t; b < BATCH; b += 256) {
        float x = dotp[b] - dotn[b];
        float ls = fminf(x, 0.0f) - log1pf(expf(-fabsf(x)));
        mf += ls;
        s += sqs[b];
    }
    smf[t] = mf; ssq[t] = s;
    __syncthreads();
    for (int off = 128; off > 0; off >>= 1) {
        if (t < off) { smf[t] += smf[t + off]; ssq[t] += ssq[t + off]; }
        __syncthreads();
    }
    if (t == 0) {
        float mf_loss = -smf[0] / (float)BATCH;
        float reg = 0.5f * ssq[0];
        float emb_loss = (float)1e-4 * reg / (float)BATCH;
        out[0] = mf_loss + emb_loss;
        out[1] = mf_loss;
        out[2] = emb_loss;
    }
}

// ---------------- launch ----------------
extern "C" void kernel_launch(void* const* d_in, const int* in_sizes, int n_in,
                              void* d_out, int out_size, void* d_ws, size_t ws_size,
                              hipStream_t stream) {
    const int*   erow  = (const int*)d_in[0];
    const int*   ecol  = (const int*)d_in[1];
    const float* evals = (const float*)d_in[2];
    const float* uemb  = (const float*)d_in[3];
    const float* iemb  = (const float*)d_in[4];
    const int*   uid   = (const int*)d_in[5];
    const int*   iid   = (const int*)d_in[6];
    const int*   nid   = (const int*)d_in[7];
    const float* Wg[3] = {(const float*)d_in[8],  (const float*)d_in[12], (const float*)d_in[16]};
    const float* bg[3] = {(const float*)d_in[9],  (const float*)d_in[13], (const float*)d_in[17]};
    const float* Wb[3] = {(const float*)d_in[10], (const float*)d_in[14], (const float*)d_in[18]};
    const float* bb[3] = {(const float*)d_in[11], (const float*)d_in[15], (const float*)d_in[19]};

    // workspace layout (~132.6 MB, 8B-aligned blocks first)
    uint2*    cv       = (uint2*)d_ws;                           // 2M uint2 (16 MB)
    float*    side     = (float*)(cv + NNZ);                     // 19.2M f32 (76.8 MB)
    uint16_t* ego      = (uint16_t*)(side + (size_t)N_NODES * EMB); // 19.2M bf16 (38.4 MB)
    uint32_t* cursor   = (uint32_t*)(ego + (size_t)N_NODES * EMB);  // 300000 u32
    uint32_t* partials = cursor + N_NODES;                       // 1024
    float*    dotp     = (float*)(partials + 1024);              // 4096
    float*    dotn     = dotp + BATCH;
    float*    sqs      = dotn + BATCH;
    size_t needed = (size_t)NNZ * 8 + (size_t)N_NODES * EMB * 4
                  + (size_t)N_NODES * EMB * 2
                  + ((size_t)N_NODES + 1024 + 3 * BATCH) * 4;
    if (ws_size < needed) return;

    // host-side JAX key derivation: key(42) = (0,42)
    uint32_t a0, b0, a1, b1;
    threefry2x32(0u, 42u, 0u, 2u, a0, b0);   // split block 0
    threefry2x32(0u, 42u, 1u, 3u, a1, b1);   // split block 1
    uint32_t knode0 = a0, knode1 = a1;       // k_node
    uint32_t kmsg0  = b0, kmsg1  = b1;       // k_msg
    uint32_t mk[6];
    for (uint32_t k = 0; k < 3; ++k)
        threefry2x32(kmsg0, kmsg1, 0u, k, mk[2 * k], mk[2 * k + 1]);

    hipMemsetAsync(cursor, 0, (size_t)N_NODES * 4, stream);
    hipMemsetAsync(dotp, 0, 3 * BATCH * 4, stream);

    // ego (bf16) init + CSR build over kept edges
    k_conv<<<(N_NODES * EMB / 4 + 255) / 256, 256, 0, stream>>>(uemb, iemb, ego);
    const int SCAN_BLOCKS = (N_NODES + 1023) / 1024;  // 293
    k_hist<<<(NNZ + 255) / 256, 256, 0, stream>>>(erow, cursor, knode0, knode1);
    k_scan1<<<SCAN_BLOCKS, 1024, 0, stream>>>(cursor, partials);
    k_scan2<<<1, 1024, 0, stream>>>(partials, SCAN_BLOCKS);
    k_scan3<<<SCAN_BLOCKS, 1024, 0, stream>>>(cursor, partials);
    k_place<<<(NNZ + 255) / 256, 256, 0, stream>>>(erow, ecol, evals, cursor, cv,
                                                   knode0, knode1);

    // segment 0: raw initial embeddings (fp32, exact)
    k_segacc<<<BATCH * 64 / 256, 256, 0, stream>>>(uemb, iemb, uid, iid, nid,
                                                   dotp, dotn, sqs, 0, 1);

    for (int k = 0; k < 3; ++k) {
        k_spmv<<<2048, 256, 0, stream>>>(ego, side, cursor, cv);
        k_dense<<<1280, 256, 0, stream>>>(ego, side, Wg[k], bg[k], Wb[k], bb[k],
                                          mk[2 * k], mk[2 * k + 1]);
        k_segacc<<<BATCH * 64 / 256, 256, 0, stream>>>(ego, ego + (size_t)USER_NUM * EMB,
                                                       uid, iid, nid, dotp, dotn, sqs, 1, 0);
    }
    k_finalize<<<1, 256, 0, stream>>>(dotp, dotn, sqs, (float*)d_out);
}

// Round 6
// 776.291 us; speedup vs baseline: 2.9483x; 1.4198x over previous
//
#include <hip/hip_runtime.h>
#include <stdint.h>

#define USER_NUM 100000
#define ITEM_NUM 200000
#define N_NODES  300000
#define EMB      64
#define NNZ      2000000
#define BATCH    4096
#define R1M      1000000u        // NNZ/2, threefry pair offset for edge dropout
#define HALF_MSG 9600000u        // N_NODES*EMB/2, pair offset for msg dropout
#define HALF_N   150000          // node pairing offset = HALF_MSG/64
#define INVK     1.1111111111111112f  // 1/0.9

typedef short short8 __attribute__((ext_vector_type(8)));
typedef float f32x4  __attribute__((ext_vector_type(4)));

// ---------------- threefry2x32 (exact JAX replica) ----------------
__host__ __device__ inline uint32_t rotl32(uint32_t v, int r) {
    return (v << r) | (v >> (32 - r));
}

__host__ __device__ inline void threefry2x32(uint32_t k0, uint32_t k1,
                                             uint32_t x0, uint32_t x1,
                                             uint32_t& o0, uint32_t& o1) {
    uint32_t k2 = k0 ^ k1 ^ 0x1BD11BDAu;
    x0 += k0; x1 += k1;
#define TF_R(r) { x0 += x1; x1 = rotl32(x1, r); x1 ^= x0; }
    TF_R(13) TF_R(15) TF_R(26) TF_R(6)
    x0 += k1; x1 += k2 + 1u;
    TF_R(17) TF_R(29) TF_R(16) TF_R(24)
    x0 += k2; x1 += k0 + 2u;
    TF_R(13) TF_R(15) TF_R(26) TF_R(6)
    x0 += k0; x1 += k1 + 3u;
    TF_R(17) TF_R(29) TF_R(16) TF_R(24)
    x0 += k1; x1 += k2 + 4u;
    TF_R(13) TF_R(15) TF_R(26) TF_R(6)
    x0 += k2; x1 += k0 + 5u;
#undef TF_R
    o0 = x0; o1 = x1;
}

__host__ __device__ inline float tf_uniform(uint32_t bits) {
    uint32_t fb = (bits >> 9) | 0x3f800000u;
    return __builtin_bit_cast(float, fb) - 1.0f;
}

__device__ inline bool edge_keep(uint32_t e, uint32_t kn0, uint32_t kn1) {
    uint32_t x0 = (e < R1M) ? e : e - R1M;
    uint32_t o0, o1;
    threefry2x32(kn0, kn1, x0, x0 + R1M, o0, o1);
    uint32_t bits = (e < R1M) ? o0 : o1;
    return tf_uniform(bits) < 0.9f;
}

// ---------------- bf16 helpers ----------------
__device__ inline float bf2f(uint16_t u) {
    uint32_t x = ((uint32_t)u) << 16;
    return __builtin_bit_cast(float, x);
}
__device__ inline uint16_t f2bf(float f) {   // round-to-nearest-even
    uint32_t x = __builtin_bit_cast(uint32_t, f);
    uint32_t r = (x + 0x7FFFu + ((x >> 16) & 1u)) >> 16;
    return (uint16_t)r;
}

// ---------------- ego init: concat(uemb,iemb) -> bf16 ----------------
__global__ __launch_bounds__(256) void k_conv(const float* __restrict__ u,
                                              const float* __restrict__ it,
                                              uint16_t* __restrict__ dst) {
    int i = blockIdx.x * 256 + threadIdx.x;     // quad index
    const int TOT = N_NODES * EMB / 4;          // 4.8M
    if (i >= TOT) return;
    const int UQ = USER_NUM * EMB / 4;
    float4 f = (i < UQ) ? ((const float4*)u)[i] : ((const float4*)it)[i - UQ];
    ushort4 o;
    o.x = f2bf(f.x); o.y = f2bf(f.y); o.z = f2bf(f.z); o.w = f2bf(f.w);
    ((ushort4*)dst)[i] = o;
}

// ---------------- CSR build (kept edges only) ----------------
__global__ __launch_bounds__(256) void k_hist(const int* __restrict__ erow,
                                              uint32_t* __restrict__ cnt,
                                              uint32_t kn0, uint32_t kn1) {
    int e = blockIdx.x * 256 + threadIdx.x;
    if (e < NNZ && edge_keep((uint32_t)e, kn0, kn1))
        atomicAdd(&cnt[erow[e]], 1u);
}

__global__ __launch_bounds__(1024) void k_scan1(uint32_t* __restrict__ cnt,
                                                uint32_t* __restrict__ partials) {
    __shared__ uint32_t sh[1024];
    int t = threadIdx.x;
    int i = blockIdx.x * 1024 + t;
    uint32_t x = (i < N_NODES) ? cnt[i] : 0u;
    sh[t] = x;
    __syncthreads();
    for (int off = 1; off < 1024; off <<= 1) {
        uint32_t y = (t >= off) ? sh[t - off] : 0u;
        __syncthreads();
        sh[t] += y;
        __syncthreads();
    }
    if (i < N_NODES) cnt[i] = sh[t] - x;
    if (t == 1023) partials[blockIdx.x] = sh[t];
}

__global__ __launch_bounds__(1024) void k_scan2(uint32_t* __restrict__ partials,
                                                int nblocks) {
    __shared__ uint32_t sh[1024];
    int t = threadIdx.x;
    uint32_t x = (t < nblocks) ? partials[t] : 0u;
    sh[t] = x;
    __syncthreads();
    for (int off = 1; off < 1024; off <<= 1) {
        uint32_t y = (t >= off) ? sh[t - off] : 0u;
        __syncthreads();
        sh[t] += y;
        __syncthreads();
    }
    if (t < nblocks) partials[t] = sh[t] - x;
}

__global__ __launch_bounds__(1024) void k_scan3(uint32_t* __restrict__ cnt,
                                                const uint32_t* __restrict__ partials) {
    int i = blockIdx.x * 1024 + threadIdx.x;
    if (i < N_NODES) cnt[i] += partials[blockIdx.x];
}

// writes packed (col, val*INVK) at sorted position
__global__ __launch_bounds__(256) void k_place(const int* __restrict__ erow,
                                               const int* __restrict__ ecol,
                                               const float* __restrict__ evals,
                                               uint32_t* __restrict__ cursor,
                                               uint2* __restrict__ cv,
                                               uint32_t kn0, uint32_t kn1) {
    int e = blockIdx.x * 256 + threadIdx.x;
    if (e >= NNZ) return;
    if (!edge_keep((uint32_t)e, kn0, kn1)) return;
    int r = erow[e];
    uint32_t pos = atomicAdd(&cursor[r], 1u);
    uint2 p;
    p.x = (uint32_t)ecol[e];
    p.y = __builtin_bit_cast(uint32_t, evals[e] * INVK);
    cv[pos] = p;
}

// -------- SPMV: side[n] = sum_e v[e] * ego[col[e]]  (wave per row, bf16) ----
__global__ __launch_bounds__(256) void k_spmv(const uint16_t* __restrict__ ego,
                                              float* __restrict__ side,
                                              const uint32_t* __restrict__ cursor,
                                              const uint2* __restrict__ cv) {
    int lane = threadIdx.x & 63;
    int wave = (blockIdx.x * 256 + threadIdx.x) >> 6;
    int nw = (gridDim.x * 256) >> 6;
    for (int n = wave; n < N_NODES; n += nw) {
        uint32_t end = cursor[n];
        uint32_t start = (n > 0) ? cursor[n - 1] : 0u;
        float acc = 0.0f;
        for (uint32_t base = start; base < end; base += 64) {
            int m = (int)min(64u, end - base);
            int c = 0; float v = 0.0f;
            if (lane < m) {
                uint2 p = cv[base + lane];
                c = (int)p.x;
                v = __builtin_bit_cast(float, p.y);
            }
            for (int j0 = 0; j0 < m; j0 += 8) {
                int jm = min(8, m - j0);
                float g[8];
#pragma unroll
                for (int u = 0; u < 8; ++u)
                    if (u < jm) {
                        int cj = __shfl(c, j0 + u, 64);
                        g[u] = bf2f(ego[(size_t)cj * 64 + lane]);
                    }
#pragma unroll
                for (int u = 0; u < 8; ++u)
                    if (u < jm) {
                        float vj = __shfl(v, j0 + u, 64);
                        acc = fmaf(vj, g[u], acc);
                    }
            }
        }
        side[(size_t)n * 64 + lane] = acc;
    }
}

// -------- MFMA frag builders --------
__device__ inline short8 frag_s(f32x4 lo, f32x4 hi) {
    short8 r;
    r[0] = (short)f2bf(lo[0]); r[1] = (short)f2bf(lo[1]);
    r[2] = (short)f2bf(lo[2]); r[3] = (short)f2bf(lo[3]);
    r[4] = (short)f2bf(hi[0]); r[5] = (short)f2bf(hi[1]);
    r[6] = (short)f2bf(hi[2]); r[7] = (short)f2bf(hi[3]);
    return r;
}
__device__ inline short8 frag_t(f32x4 lo, f32x4 hi, uint4 eg) {
    short8 r;
    r[0] = (short)f2bf(lo[0] * bf2f((uint16_t)(eg.x & 0xffffu)));
    r[1] = (short)f2bf(lo[1] * bf2f((uint16_t)(eg.x >> 16)));
    r[2] = (short)f2bf(lo[2] * bf2f((uint16_t)(eg.y & 0xffffu)));
    r[3] = (short)f2bf(lo[3] * bf2f((uint16_t)(eg.y >> 16)));
    r[4] = (short)f2bf(hi[0] * bf2f((uint16_t)(eg.z & 0xffffu)));
    r[5] = (short)f2bf(hi[1] * bf2f((uint16_t)(eg.z >> 16)));
    r[6] = (short)f2bf(hi[2] * bf2f((uint16_t)(eg.w & 0xffffu)));
    r[7] = (short)f2bf(hi[3] * bf2f((uint16_t)(eg.w >> 16)));
    return r;
}

// -------- dense via MFMA: [s | ego*s] (Nx128) @ [Wg;Wb] (128x64), in-place --
// Wave processes pair-tile (16 rows at n0, 16 rows at n0+150000); one threefry
// per element-pair serves both tiles (JAX random_bits o0/o1 structure).
__global__ __launch_bounds__(256) void k_dense_mfma(
        uint16_t* __restrict__ ego, const float* __restrict__ side,
        const float* __restrict__ Wg, const float* __restrict__ bg,
        const float* __restrict__ Wb, const float* __restrict__ bb,
        uint32_t km0, uint32_t km1) {
    int lane = threadIdx.x & 63;
    int wave = (blockIdx.x * 256 + threadIdx.x) >> 6;
    int nw = (gridDim.x * 256) >> 6;
    int m = lane & 15;     // A row within tile / C col within tile
    int g = lane >> 4;     // k-group (A) / row-group (C)

    // B frags: W[128][64] = [Wg;Wb]; bfr[kk][nt][i] = W[32kk+8g+i][16nt+m]
    short8 bfr[4][4];
#pragma unroll
    for (int kk = 0; kk < 4; ++kk) {
        const float* W = (kk < 2) ? Wg : Wb;
        int krow = (kk & 1) * 32 + 8 * g;
#pragma unroll
        for (int nt = 0; nt < 4; ++nt) {
#pragma unroll
            for (int i = 0; i < 8; ++i)
                bfr[kk][nt][i] = (short)f2bf(W[(krow + i) * 64 + 16 * nt + m]);
        }
    }
    float bias[4];
#pragma unroll
    for (int nt = 0; nt < 4; ++nt)
        bias[nt] = bg[16 * nt + m] + bb[16 * nt + m];

    for (int tile = wave; tile < HALF_N / 16; tile += nw) {
        int n0 = tile * 16;
        uint32_t keepB = 0;
        // ---------------- tile A (rows n0..n0+15) ----------------
        {
            const float*    srow = side + (size_t)(n0 + m) * 64;
            const uint16_t* erw  = ego  + (size_t)(n0 + m) * 64;
            f32x4 s0a = *(const f32x4*)(srow + 8 * g);
            f32x4 s0b = *(const f32x4*)(srow + 8 * g + 4);
            f32x4 s1a = *(const f32x4*)(srow + 32 + 8 * g);
            f32x4 s1b = *(const f32x4*)(srow + 36 + 8 * g);
            uint4 e0 = *(const uint4*)(erw + 8 * g);
            uint4 e1 = *(const uint4*)(erw + 32 + 8 * g);
            short8 a0 = frag_s(s0a, s0b);
            short8 a1 = frag_s(s1a, s1b);
            short8 a2 = frag_t(s0a, s0b, e0);
            short8 a3 = frag_t(s1a, s1b, e1);
            f32x4 acc[4];
#pragma unroll
            for (int nt = 0; nt < 4; ++nt) {
                acc[nt] = (f32x4)(0.0f);
                acc[nt] = __builtin_amdgcn_mfma_f32_16x16x32_bf16(a0, bfr[0][nt], acc[nt], 0, 0, 0);
                acc[nt] = __builtin_amdgcn_mfma_f32_16x16x32_bf16(a1, bfr[1][nt], acc[nt], 0, 0, 0);
                acc[nt] = __builtin_amdgcn_mfma_f32_16x16x32_bf16(a2, bfr[2][nt], acc[nt], 0, 0, 0);
                acc[nt] = __builtin_amdgcn_mfma_f32_16x16x32_bf16(a3, bfr[3][nt], acc[nt], 0, 0, 0);
            }
#pragma unroll
            for (int nt = 0; nt < 4; ++nt) {
#pragma unroll
                for (int i = 0; i < 4; ++i) {
                    int row = n0 + g * 4 + i;
                    int col = 16 * nt + m;
                    float h = acc[nt][i] + bias[nt];
                    h = (h >= 0.0f) ? h : 0.2f * h;
                    uint32_t j = (uint32_t)row * 64u + (uint32_t)col;  // < HALF_MSG
                    uint32_t o0, o1;
                    threefry2x32(km0, km1, j, j + HALF_MSG, o0, o1);
                    bool kA = tf_uniform(o0) < 0.9f;
                    keepB |= (uint32_t)(tf_uniform(o1) < 0.9f) << (nt * 4 + i);
                    ego[(size_t)row * 64 + col] = f2bf(kA ? h * INVK : 0.0f);
                }
            }
        }
        // ---------------- tile B (rows n0+150000..+15) ----------------
        {
            int R = n0 + HALF_N;
            const float*    srow = side + (size_t)(R + m) * 64;
            const uint16_t* erw  = ego  + (size_t)(R + m) * 64;
            f32x4 s0a = *(const f32x4*)(srow + 8 * g);
            f32x4 s0b = *(const f32x4*)(srow + 8 * g + 4);
            f32x4 s1a = *(const f32x4*)(srow + 32 + 8 * g);
            f32x4 s1b = *(const f32x4*)(srow + 36 + 8 * g);
            uint4 e0 = *(const uint4*)(erw + 8 * g);
            uint4 e1 = *(const uint4*)(erw + 32 + 8 * g);
            short8 a0 = frag_s(s0a, s0b);
            short8 a1 = frag_s(s1a, s1b);
            short8 a2 = frag_t(s0a, s0b, e0);
            short8 a3 = frag_t(s1a, s1b, e1);
            f32x4 acc[4];
#pragma unroll
            for (int nt = 0; nt < 4; ++nt) {
                acc[nt] = (f32x4)(0.0f);
                acc[nt] = __builtin_amdgcn_mfma_f32_16x16x32_bf16(a0, bfr[0][nt], acc[nt], 0, 0, 0);
                acc[nt] = __builtin_amdgcn_mfma_f32_16x16x32_bf16(a1, bfr[1][nt], acc[nt], 0, 0, 0);
                acc[nt] = __builtin_amdgcn_mfma_f32_16x16x32_bf16(a2, bfr[2][nt], acc[nt], 0, 0, 0);
                acc[nt] = __builtin_amdgcn_mfma_f32_16x16x32_bf16(a3, bfr[3][nt], acc[nt], 0, 0, 0);
            }
#pragma unroll
            for (int nt = 0; nt < 4; ++nt) {
#pragma unroll
                for (int i = 0; i < 4; ++i) {
                    int row = R + g * 4 + i;
                    int col = 16 * nt + m;
                    float h = acc[nt][i] + bias[nt];
                    h = (h >= 0.0f) ? h : 0.2f * h;
                    bool kB = (keepB >> (nt * 4 + i)) & 1u;
                    ego[(size_t)row * 64 + col] = f2bf(kB ? h * INVK : 0.0f);
                }
            }
        }
    }
}

// ---------------- batch accumulation & finalize ----------------
__device__ inline float wred64(float v) {
#pragma unroll
    for (int m = 32; m >= 1; m >>= 1) v += __shfl_xor(v, m, 64);
    return v;
}

__global__ __launch_bounds__(256) void k_segacc(const void* __restrict__ ua_,
                                                const void* __restrict__ ia_,
                                                const int* __restrict__ uid,
                                                const int* __restrict__ iid,
                                                const int* __restrict__ nid,
                                                float* __restrict__ dotp,
                                                float* __restrict__ dotn,
                                                float* __restrict__ sqs,
                                                int normalize, int f32) {
    int gt = blockIdx.x * 256 + threadIdx.x;
    int w = gt >> 6, lane = gt & 63;
    if (w >= BATCH) return;
    int u = uid[w], p = iid[w], n = nid[w];
    float eu, ep, en;
    if (f32) {
        const float* ua = (const float*)ua_;
        const float* ia = (const float*)ia_;
        eu = ua[(size_t)u * EMB + lane];
        ep = ia[(size_t)p * EMB + lane];
        en = ia[(size_t)n * EMB + lane];
    } else {
        const uint16_t* ua = (const uint16_t*)ua_;
        const uint16_t* ia = (const uint16_t*)ia_;
        eu = bf2f(ua[(size_t)u * EMB + lane]);
        ep = bf2f(ia[(size_t)p * EMB + lane]);
        en = bf2f(ia[(size_t)n * EMB + lane]);
    }
    if (normalize) {
        float su = wred64(eu * eu);
        float sp = wred64(ep * ep);
        float sn = wred64(en * en);
        eu /= fmaxf(sqrtf(su), 1e-12f);
        ep /= fmaxf(sqrtf(sp), 1e-12f);
        en /= fmaxf(sqrtf(sn), 1e-12f);
    }
    float dp = wred64(eu * ep);
    float dn = wred64(eu * en);
    float s3 = wred64(eu * eu + ep * ep + en * en);
    if (lane == 0) {
        dotp[w] += dp;
        dotn[w] += dn;
        sqs[w]  += s3;
    }
}

__global__ __launch_bounds__(256) void k_finalize(const float* __restrict__ dotp,
                                                  const float* __restrict__ dotn,
                                                  const float* __restrict__ sqs,
                                                  float* __restrict__ out) {
    __shared__ float smf[256], ssq[256];
    int t = threadIdx.x;
    float mf = 0.0f, s = 0.0f;
    for (int b = t; b < BATCH; b += 256) {
        float x = dotp[b] - dotn[b];
        float ls = fminf(x, 0.0f) - log1pf(expf(-fabsf(x)));
        mf += ls;
        s += sqs[b];
    }
    smf[t] = mf; ssq[t] = s;
    __syncthreads();
    for (int off = 128; off > 0; off >>= 1) {
        if (t < off) { smf[t] += smf[t + off]; ssq[t] += ssq[t + off]; }
        __syncthreads();
    }
    if (t == 0) {
        float mf_loss = -smf[0] / (float)BATCH;
        float reg = 0.5f * ssq[0];
        float emb_loss = (float)1e-4 * reg / (float)BATCH;
        out[0] = mf_loss + emb_loss;
        out[1] = mf_loss;
        out[2] = emb_loss;
    }
}

// ---------------- launch ----------------
extern "C" void kernel_launch(void* const* d_in, const int* in_sizes, int n_in,
                              void* d_out, int out_size, void* d_ws, size_t ws_size,
                              hipStream_t stream) {
    const int*   erow  = (const int*)d_in[0];
    const int*   ecol  = (const int*)d_in[1];
    const float* evals = (const float*)d_in[2];
    const float* uemb  = (const float*)d_in[3];
    const float* iemb  = (const float*)d_in[4];
    const int*   uid   = (const int*)d_in[5];
    const int*   iid   = (const int*)d_in[6];
    const int*   nid   = (const int*)d_in[7];
    const float* Wg[3] = {(const float*)d_in[8],  (const float*)d_in[12], (const float*)d_in[16]};
    const float* bg[3] = {(const float*)d_in[9],  (const float*)d_in[13], (const float*)d_in[17]};
    const float* Wb[3] = {(const float*)d_in[10], (const float*)d_in[14], (const float*)d_in[18]};
    const float* bb[3] = {(const float*)d_in[11], (const float*)d_in[15], (const float*)d_in[19]};

    // workspace layout (~132.6 MB, 8B-aligned blocks first)
    uint2*    cv       = (uint2*)d_ws;                           // 2M uint2 (16 MB)
    float*    side     = (float*)(cv + NNZ);                     // 19.2M f32 (76.8 MB)
    uint16_t* ego      = (uint16_t*)(side + (size_t)N_NODES * EMB); // 19.2M bf16 (38.4 MB)
    uint32_t* cursor   = (uint32_t*)(ego + (size_t)N_NODES * EMB);  // 300000 u32
    uint32_t* partials = cursor + N_NODES;                       // 1024
    float*    dotp     = (float*)(partials + 1024);              // 4096
    float*    dotn     = dotp + BATCH;
    float*    sqs      = dotn + BATCH;
    size_t needed = (size_t)NNZ * 8 + (size_t)N_NODES * EMB * 4
                  + (size_t)N_NODES * EMB * 2
                  + ((size_t)N_NODES + 1024 + 3 * BATCH) * 4;
    if (ws_size < needed) return;

    // host-side JAX key derivation: key(42) = (0,42)
    uint32_t a0, b0, a1, b1;
    threefry2x32(0u, 42u, 0u, 2u, a0, b0);   // split block 0
    threefry2x32(0u, 42u, 1u, 3u, a1, b1);   // split block 1
    uint32_t knode0 = a0, knode1 = a1;       // k_node
    uint32_t kmsg0  = b0, kmsg1  = b1;       // k_msg
    uint32_t mk[6];
    for (uint32_t k = 0; k < 3; ++k)
        threefry2x32(kmsg0, kmsg1, 0u, k, mk[2 * k], mk[2 * k + 1]);

    hipMemsetAsync(cursor, 0, (size_t)N_NODES * 4, stream);
    hipMemsetAsync(dotp, 0, 3 * BATCH * 4, stream);

    // ego (bf16) init + CSR build over kept edges
    k_conv<<<(N_NODES * EMB / 4 + 255) / 256, 256, 0, stream>>>(uemb, iemb, ego);
    const int SCAN_BLOCKS = (N_NODES + 1023) / 1024;  // 293
    k_hist<<<(NNZ + 255) / 256, 256, 0, stream>>>(erow, cursor, knode0, knode1);
    k_scan1<<<SCAN_BLOCKS, 1024, 0, stream>>>(cursor, partials);
    k_scan2<<<1, 1024, 0, stream>>>(partials, SCAN_BLOCKS);
    k_scan3<<<SCAN_BLOCKS, 1024, 0, stream>>>(cursor, partials);
    k_place<<<(NNZ + 255) / 256, 256, 0, stream>>>(erow, ecol, evals, cursor, cv,
                                                   knode0, knode1);

    // segment 0: raw initial embeddings (fp32, exact)
    k_segacc<<<BATCH * 64 / 256, 256, 0, stream>>>(uemb, iemb, uid, iid, nid,
                                                   dotp, dotn, sqs, 0, 1);

    for (int k = 0; k < 3; ++k) {
        k_spmv<<<2048, 256, 0, stream>>>(ego, side, cursor, cv);
        k_dense_mfma<<<768, 256, 0, stream>>>(ego, side, Wg[k], bg[k], Wb[k], bb[k],
                                              mk[2 * k], mk[2 * k + 1]);
        k_segacc<<<BATCH * 64 / 256, 256, 0, stream>>>(ego, ego + (size_t)USER_NUM * EMB,
                                                       uid, iid, nid, dotp, dotn, sqs, 1, 0);
    }
    k_finalize<<<1, 256, 0, stream>>>(dotp, dotn, sqs, (float*)d_out);
}